// Round 8
// baseline (1113.106 us; speedup 1.0000x reference)
//
#include <hip/hip_runtime.h>
#include <hip/hip_fp16.h>

#define DEVFN __device__ __forceinline__

struct PlanePtrs { const float* p[9]; };

// Plane geometry (compile-time):
//   planes 0..5 temporal (tp0..tp5), 6..8 spatial (sp0..sp2)
//   W = 128 for all planes; H = 128 except planes 2,4,5 (H=100)
__constant__ const int g_H[9] = {128,128,100,128,100,100,128,128,128};
__constant__ const int g_A[9] = {0,0,0,1,1,2,0,0,1};
__constant__ const int g_B[9] = {1,2,3,2,3,3,1,2,2};
// absolute texel prefix boundaries (monotone -> order-safe plane select)
__constant__ const int g_PRE[10] = {0,16384,32768,45568,61952,74752,87552,103936,120320,136704};
// transposed-plane base offsets in uint4 units (= g_PRE[pl] * 8)
__constant__ const int g_OFF4[9] = {0,131072,262144,364544,495616,598016,700416,831488,962560};

static const int    TOTAL_TEXELS = 136704;            // g_PRE[9]
static const size_t WS_PLANES    = 17498112ull;       // fp16 planes bytes
static const int    NBINS        = 2048;
static const int    NHB          = 256;               // histogram blocks

// ---------------------------------------------------------------------------
// Kernel 1: transpose planes [64,H,W] f32 -> [H*W, 64] f16 (verified round 2)
// ---------------------------------------------------------------------------
__global__ __launch_bounds__(256) void k_transpose(PlanePtrs ptrs, __half* __restrict__ dst)
{
    int gid = blockIdx.x * 256 + threadIdx.x;

    int pl = 0;
    #pragma unroll
    for (int i = 1; i < 9; ++i) if (gid >= g_PRE[i]) pl = i;
    int tx   = gid - g_PRE[pl];
    int nTex = g_PRE[pl + 1] - g_PRE[pl];

    const float* src = ptrs.p[0];
    #pragma unroll
    for (int i = 1; i < 9; ++i) if (pl == i) src = ptrs.p[i];
    src += tx;

    uint4* __restrict__ out4 = reinterpret_cast<uint4*>(dst) + (size_t)gid * 8;
    #pragma unroll
    for (int j = 0; j < 8; ++j) {
        float f0 = src[(8*j+0)*nTex];
        float f1 = src[(8*j+1)*nTex];
        float f2 = src[(8*j+2)*nTex];
        float f3 = src[(8*j+3)*nTex];
        float f4 = src[(8*j+4)*nTex];
        float f5 = src[(8*j+5)*nTex];
        float f6 = src[(8*j+6)*nTex];
        float f7 = src[(8*j+7)*nTex];
        uint4 u;
        u.x = __builtin_bit_cast(unsigned int, __floats2half2_rn(f0, f1));
        u.y = __builtin_bit_cast(unsigned int, __floats2half2_rn(f2, f3));
        u.z = __builtin_bit_cast(unsigned int, __floats2half2_rn(f4, f5));
        u.w = __builtin_bit_cast(unsigned int, __floats2half2_rn(f6, f7));
        out4[j] = u;
    }
}

// ---------------------------------------------------------------------------
// Sorting prepass (two-level, LDS atomics only):
//   key = x:3 | y:3 | z:3 | t:2  (2048 bins)
//   k_hist2: per-block LDS histogram -> blkhist[blk][bin]
//   k_scanA: per-bin exclusive scan over blocks (in place) + bintotal
//   k_scanB: exclusive scan over bins -> binstart
//   k_fill2: order[binstart + blkoff + lds_rank] = original index
// Index-only sort; each point's output value/position depend only on itself
// -> deterministic output despite atomic rank ordering.
// ---------------------------------------------------------------------------
DEVFN int point_key(float4 in, float a0x, float a0y, float a0z,
                    float isx, float isy, float isz)
{
    float x = (in.x - a0x) * isx;
    float y = (in.y - a0y) * isy;
    float z = (in.z - a0z) * isz;
    int xc = min(7, max(0, (int)(x * 8.0f)));
    int yc = min(7, max(0, (int)(y * 8.0f)));
    int zc = min(7, max(0, (int)(z * 8.0f)));
    int tc = min(3, max(0, (int)(in.w * 4.0f)));
    return (((xc << 3) | yc) << 3 | zc) << 2 | tc;
}

__global__ __launch_bounds__(256) void k_hist2(const float4* __restrict__ inp,
                                               const float* __restrict__ aabb,
                                               int N, int chunk,
                                               int* __restrict__ blkhist)
{
    __shared__ int hc[NBINS];
    const int tid = threadIdx.x, blk = blockIdx.x;
    #pragma unroll
    for (int j = 0; j < NBINS / 256; ++j) hc[tid + j * 256] = 0;
    __syncthreads();

    float a0x = aabb[0], a0y = aabb[1], a0z = aabb[2];
    float isx = 1.0f / (aabb[3] - a0x), isy = 1.0f / (aabb[4] - a0y), isz = 1.0f / (aabb[5] - a0z);

    int end = min(N, (blk + 1) * chunk);
    for (int i = blk * chunk + tid; i < end; i += 256)
        atomicAdd(&hc[point_key(inp[i], a0x, a0y, a0z, isx, isy, isz)], 1);

    __syncthreads();
    #pragma unroll
    for (int j = 0; j < NBINS / 256; ++j)
        blkhist[blk * NBINS + tid + j * 256] = hc[tid + j * 256];
}

__global__ __launch_bounds__(256) void k_scanA(int* __restrict__ blkhist,
                                               int* __restrict__ bintotal)
{
    int bin = blockIdx.x * 256 + threadIdx.x;   // 2048 threads
    int run = 0;
    for (int b = 0; b < NHB; ++b) {
        int v = blkhist[b * NBINS + bin];
        blkhist[b * NBINS + bin] = run;
        run += v;
    }
    bintotal[bin] = run;
}

__global__ __launch_bounds__(256) void k_scanB(const int* __restrict__ bintotal,
                                               int* __restrict__ binstart)
{
    int t = threadIdx.x;
    int v[8]; int sum = 0;
    #pragma unroll
    for (int j = 0; j < 8; ++j) { v[j] = bintotal[t * 8 + j]; sum += v[j]; }

    int lane = t & 63, w = t >> 6;
    int x = sum;
    #pragma unroll
    for (int d = 1; d < 64; d <<= 1) {
        int y = __shfl_up(x, d);
        if (lane >= d) x += y;
    }
    __shared__ int wsum[4];
    if (lane == 63) wsum[w] = x;
    __syncthreads();
    int woff = 0;
    for (int i = 0; i < w; ++i) woff += wsum[i];
    int run = woff + x - sum;
    #pragma unroll
    for (int j = 0; j < 8; ++j) { binstart[t * 8 + j] = run; run += v[j]; }
}

__global__ __launch_bounds__(256) void k_fill2(const float4* __restrict__ inp,
                                               const float* __restrict__ aabb,
                                               int N, int chunk,
                                               const int* __restrict__ blkhist,
                                               const int* __restrict__ binstart,
                                               int* __restrict__ order)
{
    __shared__ int hc[NBINS];
    const int tid = threadIdx.x, blk = blockIdx.x;
    #pragma unroll
    for (int j = 0; j < NBINS / 256; ++j) hc[tid + j * 256] = 0;
    __syncthreads();

    float a0x = aabb[0], a0y = aabb[1], a0z = aabb[2];
    float isx = 1.0f / (aabb[3] - a0x), isy = 1.0f / (aabb[4] - a0y), isz = 1.0f / (aabb[5] - a0z);

    int end = min(N, (blk + 1) * chunk);
    for (int i = blk * chunk + tid; i < end; i += 256) {
        int key = point_key(inp[i], a0x, a0y, a0z, isx, isy, isz);
        int lr  = atomicAdd(&hc[key], 1);
        order[binstart[key] + blkhist[blk * NBINS + key] + lr] = i;
    }
}

// ---------------------------------------------------------------------------
// Kernel 2: fused gather + MLP, 64 threads (1 wave) per 32 points.
// LDS 8.3 KB/block -> ~16 waves/CU (VGPR-capped) vs round 7's 9.
// XCD-chunked block swizzle keeps consecutive sorted bins on one XCD's L2.
// Phase A: 8 groups x 8 lanes, 4 points/group (round-2 math, verified).
// Phase B: 2 threads/point, hidden slice 32 as two h[16] chunks (round-6
//          56-VGPR shape); pair-reduce via shfl_xor(32).
// ---------------------------------------------------------------------------
DEVFN void corner4f(unsigned a, unsigned b, unsigned c, unsigned d,
                    __half2 w00, __half2 w01, __half2 w10, __half2 w11,
                    float& ax, float& ay)
{
    __half2 t = __hmul2(__builtin_bit_cast(__half2, a), w00);
    t = __hfma2(__builtin_bit_cast(__half2, b), w01, t);
    t = __hfma2(__builtin_bit_cast(__half2, c), w10, t);
    t = __hfma2(__builtin_bit_cast(__half2, d), w11, t);
    ax += __low2float(t);
    ay += __high2float(t);
}

__global__ __launch_bounds__(64) void k_main(
    const float4* __restrict__ inp,
    const float*  __restrict__ aabb,
    const __half* __restrict__ planes,
    const int*    __restrict__ order,
    int           useOrder,
    const float*  __restrict__ w0,
    const float*  __restrict__ b0,
    const float*  __restrict__ w1,
    const float*  __restrict__ b1,
    float*        __restrict__ out)
{
    __shared__ unsigned int lds[32 * 65];   // 32 pts x 64 feat-dwords, stride 65

    const int tid = threadIdx.x;
    const int g   = tid >> 3;
    const int k   = tid & 7;

    // XCD-chunked swizzle (bijective when nwg % 8 == 0)
    const int nwg = gridDim.x;
    const int bid = blockIdx.x;
    const int wid = ((nwg & 7) == 0) ? ((bid & 7) * (nwg >> 3) + (bid >> 3)) : bid;
    const int base = wid * 32;

    const int myord = useOrder ? order[base + (tid & 31)] : (base + (tid & 31));

    float a0x = aabb[0], a0y = aabb[1], a0z = aabb[2];
    float sx  = aabb[3] - a0x, sy = aabb[4] - a0y, sz = aabb[5] - a0z;

    // ---------------- Phase A: gather (4 points per group) ----------------
    for (int q = 0; q < 4; ++q) {
        const int p = g * 4 + q;                 // 0..31
        const int pidx = __shfl(myord, p);       // original index of point p
        float4 in = inp[pidx];
        float c[4];
        c[0] = (in.x - a0x) / sx * 2.0f - 1.0f;
        c[1] = (in.y - a0y) / sy * 2.0f - 1.0f;
        c[2] = (in.z - a0z) / sz * 2.0f - 1.0f;
        c[3] = in.w * 2.0f - 1.0f;

        float accT[8], accS[8];
        #pragma unroll
        for (int j = 0; j < 8; ++j) { accT[j] = 0.0f; accS[j] = 0.0f; }

        #pragma unroll
        for (int pl = 0; pl < 9; ++pl) {
            const int W = 128;
            const int H = g_H[pl];
            float fx = (c[g_A[pl]] + 1.0f) * 0.5f * (float)(W - 1);
            float fy = (c[g_B[pl]] + 1.0f) * 0.5f * (float)(H - 1);
            int x0 = min(max((int)floorf(fx), 0), W - 2);
            int y0 = min(max((int)floorf(fy), 0), H - 2);
            float wx = fx - (float)x0;
            float wy = fy - (float)y0;
            float iwx = 1.0f - wx, iwy = 1.0f - wy;

            const uint4* pb = reinterpret_cast<const uint4*>(planes)
                            + g_OFF4[pl] + ((y0 << 7) + x0) * 8 + k;
            uint4 v00 = pb[0];
            uint4 v01 = pb[8];
            uint4 v10 = pb[1024];
            uint4 v11 = pb[1032];

            __half2 w00h = __float2half2_rn(iwx * iwy);
            __half2 w01h = __float2half2_rn(wx  * iwy);
            __half2 w10h = __float2half2_rn(iwx * wy);
            __half2 w11h = __float2half2_rn(wx  * wy);

            if (pl < 6) {
                corner4f(v00.x, v01.x, v10.x, v11.x, w00h, w01h, w10h, w11h, accT[0], accT[1]);
                corner4f(v00.y, v01.y, v10.y, v11.y, w00h, w01h, w10h, w11h, accT[2], accT[3]);
                corner4f(v00.z, v01.z, v10.z, v11.z, w00h, w01h, w10h, w11h, accT[4], accT[5]);
                corner4f(v00.w, v01.w, v10.w, v11.w, w00h, w01h, w10h, w11h, accT[6], accT[7]);
            } else {
                corner4f(v00.x, v01.x, v10.x, v11.x, w00h, w01h, w10h, w11h, accS[0], accS[1]);
                corner4f(v00.y, v01.y, v10.y, v11.y, w00h, w01h, w10h, w11h, accS[2], accS[3]);
                corner4f(v00.z, v01.z, v10.z, v11.z, w00h, w01h, w10h, w11h, accS[4], accS[5]);
                corner4f(v00.w, v01.w, v10.w, v11.w, w00h, w01h, w10h, w11h, accS[6], accS[7]);
            }
        }

        #pragma unroll
        for (int j = 0; j < 4; ++j) {
            lds[p * 65 +      k * 4 + j] =
                __builtin_bit_cast(unsigned int, __floats2half2_rn(accT[2*j], accT[2*j+1]));
            lds[p * 65 + 32 + k * 4 + j] =
                __builtin_bit_cast(unsigned int, __floats2half2_rn(accS[2*j], accS[2*j+1]));
        }
    }

    __syncthreads();

    // ------ Phase B: MLP, 2 threads/point, two h[16] chunks per thread ------
    const int p = tid & 31;
    const int s = tid >> 5;                       // hidden slice selector
    const unsigned int* lrow = &lds[p * 65];

    float o0 = 0.0f, o1 = 0.0f, o2 = 0.0f;

    #pragma unroll 1
    for (int jc2 = 0; jc2 < 2; ++jc2) {
        const int jc = s * 32 + jc2 * 16;
        float h[16];
        #pragma unroll
        for (int jj = 0; jj < 16; ++jj) h[jj] = b0[jc + jj];

        #pragma unroll 4
        for (int d = 0; d < 64; ++d) {
            unsigned u = lrow[d];
            __half2 hv = __builtin_bit_cast(__half2, u);
            float f0 = __low2float(hv);
            float f1 = __high2float(hv);
            const float* wr = w0 + d * 128 + jc;  // w0 rows 2d, 2d+1 (stride 64)
            #pragma unroll
            for (int jj = 0; jj < 16; ++jj) h[jj] = fmaf(f0, wr[jj], h[jj]);
            #pragma unroll
            for (int jj = 0; jj < 16; ++jj) h[jj] = fmaf(f1, wr[64 + jj], h[jj]);
        }

        #pragma unroll
        for (int jj = 0; jj < 16; ++jj) {
            float r = fmaxf(h[jj], 0.0f);
            const float* wq = w1 + (jc + jj) * 3;
            o0 = fmaf(r, wq[0], o0);
            o1 = fmaf(r, wq[1], o1);
            o2 = fmaf(r, wq[2], o2);
        }
    }

    o0 += __shfl_xor(o0, 32);
    o1 += __shfl_xor(o1, 32);
    o2 += __shfl_xor(o2, 32);

    if (s == 0) {
        long long oo = (long long)myord * 3;
        out[oo + 0] = o0 + b1[0];
        out[oo + 1] = o1 + b1[1];
        out[oo + 2] = o2 + b1[2];
    }
}

// ---------------------------------------------------------------------------
// Fallback (d_ws too small or N not divisible by 32): slow but correct.
// ---------------------------------------------------------------------------
__global__ __launch_bounds__(256) void k_fallback(
    const float4* __restrict__ inp, const float* __restrict__ aabb, PlanePtrs ptrs,
    const float* __restrict__ w0, const float* __restrict__ b0,
    const float* __restrict__ w1, const float* __restrict__ b1,
    float* __restrict__ out, int N, int start)
{
    int pidx = start + blockIdx.x * 256 + threadIdx.x;
    if (pidx >= N) return;
    float4 in = inp[pidx];
    float c[4];
    c[0] = (in.x - aabb[0]) / (aabb[3] - aabb[0]) * 2.0f - 1.0f;
    c[1] = (in.y - aabb[1]) / (aabb[4] - aabb[1]) * 2.0f - 1.0f;
    c[2] = (in.z - aabb[2]) / (aabb[5] - aabb[2]) * 2.0f - 1.0f;
    c[3] = in.w * 2.0f - 1.0f;

    float h[64];
    #pragma unroll
    for (int j = 0; j < 64; ++j) h[j] = b0[j];

    #pragma unroll
    for (int pl = 0; pl < 9; ++pl) {
        const int W = 128, H = g_H[pl];
        float fx = (c[g_A[pl]] + 1.0f) * 0.5f * (float)(W - 1);
        float fy = (c[g_B[pl]] + 1.0f) * 0.5f * (float)(H - 1);
        int x0 = min(max((int)floorf(fx), 0), W - 2);
        int y0 = min(max((int)floorf(fy), 0), H - 2);
        float wx = fx - (float)x0, wy = fy - (float)y0;
        const float* P = ptrs.p[pl];
        int off = y0 * 128 + x0;
        int HW = H * 128;
        int row = (pl < 6) ? 0 : 64;
        for (int f = 0; f < 64; ++f) {
            const float* qp = P + f * HW + off;
            float v = (qp[0] * (1.0f - wx) + qp[1] * wx) * (1.0f - wy)
                    + (qp[128] * (1.0f - wx) + qp[129] * wx) * wy;
            const float* wr = w0 + (row + f) * 64;
            #pragma unroll
            for (int j = 0; j < 64; ++j) h[j] = fmaf(v, wr[j], h[j]);
        }
    }
    float o0 = b1[0], o1 = b1[1], o2 = b1[2];
    #pragma unroll
    for (int j = 0; j < 64; ++j) {
        float r = fmaxf(h[j], 0.0f);
        o0 = fmaf(r, w1[j * 3 + 0], o0);
        o1 = fmaf(r, w1[j * 3 + 1], o1);
        o2 = fmaf(r, w1[j * 3 + 2], o2);
    }
    out[(long long)pidx * 3 + 0] = o0;
    out[(long long)pidx * 3 + 1] = o1;
    out[(long long)pidx * 3 + 2] = o2;
}

// ---------------------------------------------------------------------------
extern "C" void kernel_launch(void* const* d_in, const int* in_sizes, int n_in,
                              void* d_out, int out_size, void* d_ws, size_t ws_size,
                              hipStream_t stream)
{
    const float4* inp  = (const float4*)d_in[0];
    const float*  aabb = (const float*)d_in[1];
    PlanePtrs ptrs;
    for (int i = 0; i < 9; ++i) ptrs.p[i] = (const float*)d_in[2 + i];
    const float* w0 = (const float*)d_in[11];
    const float* b0 = (const float*)d_in[12];
    const float* w1 = (const float*)d_in[13];
    const float* b1 = (const float*)d_in[14];
    float* out = (float*)d_out;
    const int N = in_sizes[0] / 4;

    const size_t off_order = WS_PLANES;
    const size_t off_bh    = off_order + 4ull * (size_t)N;
    const size_t off_bt    = off_bh + (size_t)NHB * NBINS * 4;
    const size_t off_bs    = off_bt + NBINS * 4;
    const size_t need_sort = off_bs + NBINS * 4;

    if (ws_size >= WS_PLANES && (N % 32) == 0) {
        __half* planes = (__half*)d_ws;
        k_transpose<<<TOTAL_TEXELS / 256, 256, 0, stream>>>(ptrs, planes);

        if (ws_size >= need_sort) {
            int* order    = (int*)((char*)d_ws + off_order);
            int* blkhist  = (int*)((char*)d_ws + off_bh);
            int* bintotal = (int*)((char*)d_ws + off_bt);
            int* binstart = (int*)((char*)d_ws + off_bs);
            int chunk = (((N + NHB - 1) / NHB) + 255) / 256 * 256;

            k_hist2<<<NHB, 256, 0, stream>>>(inp, aabb, N, chunk, blkhist);
            k_scanA<<<NBINS / 256, 256, 0, stream>>>(blkhist, bintotal);
            k_scanB<<<1, 256, 0, stream>>>(bintotal, binstart);
            k_fill2<<<NHB, 256, 0, stream>>>(inp, aabb, N, chunk, blkhist, binstart, order);
            k_main<<<N / 32, 64, 0, stream>>>(inp, aabb, planes, order, 1,
                                              w0, b0, w1, b1, out);
        } else {
            k_main<<<N / 32, 64, 0, stream>>>(inp, aabb, planes, (const int*)nullptr, 0,
                                              w0, b0, w1, b1, out);
        }
    } else {
        k_fallback<<<(N + 255) / 256, 256, 0, stream>>>(inp, aabb, ptrs, w0, b0, w1, b1, out, N, 0);
    }
}

// Round 9
// 486.785 us; speedup vs baseline: 2.2867x; 2.2867x over previous
//
#include <hip/hip_runtime.h>
#include <hip/hip_fp16.h>

#define DEVFN __device__ __forceinline__

struct PlanePtrs { const float* p[9]; };

// Plane geometry (compile-time):
//   planes 0..5 temporal (tp0..tp5), 6..8 spatial (sp0..sp2)
//   W = 128 for all planes; H = 128 except planes 2,4,5 (H=100)
__constant__ const int g_H[9] = {128,128,100,128,100,100,128,128,128};
__constant__ const int g_A[9] = {0,0,0,1,1,2,0,0,1};
__constant__ const int g_B[9] = {1,2,3,2,3,3,1,2,2};
// absolute texel prefix boundaries (monotone -> order-safe plane select)
__constant__ const int g_PRE[10] = {0,16384,32768,45568,61952,74752,87552,103936,120320,136704};
// transposed-plane base offsets in uint4 units (= g_PRE[pl] * 8)
__constant__ const int g_OFF4[9] = {0,131072,262144,364544,495616,598016,700416,831488,962560};

static const int    TOTAL_TEXELS = 136704;            // g_PRE[9]
static const size_t WS_PLANES    = 17498112ull;       // fp16 planes bytes
static const int    NBINS        = 2048;
static const int    NHB          = 256;               // histogram blocks

// ---------------------------------------------------------------------------
// Kernel 1: transpose planes [64,H,W] f32 -> [H*W, 64] f16 (verified round 2)
// ---------------------------------------------------------------------------
__global__ __launch_bounds__(256) void k_transpose(PlanePtrs ptrs, __half* __restrict__ dst)
{
    int gid = blockIdx.x * 256 + threadIdx.x;

    int pl = 0;
    #pragma unroll
    for (int i = 1; i < 9; ++i) if (gid >= g_PRE[i]) pl = i;
    int tx   = gid - g_PRE[pl];
    int nTex = g_PRE[pl + 1] - g_PRE[pl];

    const float* src = ptrs.p[0];
    #pragma unroll
    for (int i = 1; i < 9; ++i) if (pl == i) src = ptrs.p[i];
    src += tx;

    uint4* __restrict__ out4 = reinterpret_cast<uint4*>(dst) + (size_t)gid * 8;
    #pragma unroll
    for (int j = 0; j < 8; ++j) {
        float f0 = src[(8*j+0)*nTex];
        float f1 = src[(8*j+1)*nTex];
        float f2 = src[(8*j+2)*nTex];
        float f3 = src[(8*j+3)*nTex];
        float f4 = src[(8*j+4)*nTex];
        float f5 = src[(8*j+5)*nTex];
        float f6 = src[(8*j+6)*nTex];
        float f7 = src[(8*j+7)*nTex];
        uint4 u;
        u.x = __builtin_bit_cast(unsigned int, __floats2half2_rn(f0, f1));
        u.y = __builtin_bit_cast(unsigned int, __floats2half2_rn(f2, f3));
        u.z = __builtin_bit_cast(unsigned int, __floats2half2_rn(f4, f5));
        u.w = __builtin_bit_cast(unsigned int, __floats2half2_rn(f6, f7));
        out4[j] = u;
    }
}

// ---------------------------------------------------------------------------
// Sorting prepass (two-level, LDS atomics only) — verified round 8.
//   key = x:3 | y:3 | z:3 | t:2  (2048 bins)
// Index-only sort; output position/value depend only on the point itself
// -> deterministic output despite atomic rank ordering.
// ---------------------------------------------------------------------------
DEVFN int point_key(float4 in, float a0x, float a0y, float a0z,
                    float isx, float isy, float isz)
{
    float x = (in.x - a0x) * isx;
    float y = (in.y - a0y) * isy;
    float z = (in.z - a0z) * isz;
    int xc = min(7, max(0, (int)(x * 8.0f)));
    int yc = min(7, max(0, (int)(y * 8.0f)));
    int zc = min(7, max(0, (int)(z * 8.0f)));
    int tc = min(3, max(0, (int)(in.w * 4.0f)));
    return (((xc << 3) | yc) << 3 | zc) << 2 | tc;
}

__global__ __launch_bounds__(256) void k_hist2(const float4* __restrict__ inp,
                                               const float* __restrict__ aabb,
                                               int N, int chunk,
                                               int* __restrict__ blkhist)
{
    __shared__ int hc[NBINS];
    const int tid = threadIdx.x, blk = blockIdx.x;
    #pragma unroll
    for (int j = 0; j < NBINS / 256; ++j) hc[tid + j * 256] = 0;
    __syncthreads();

    float a0x = aabb[0], a0y = aabb[1], a0z = aabb[2];
    float isx = 1.0f / (aabb[3] - a0x), isy = 1.0f / (aabb[4] - a0y), isz = 1.0f / (aabb[5] - a0z);

    int end = min(N, (blk + 1) * chunk);
    for (int i = blk * chunk + tid; i < end; i += 256)
        atomicAdd(&hc[point_key(inp[i], a0x, a0y, a0z, isx, isy, isz)], 1);

    __syncthreads();
    #pragma unroll
    for (int j = 0; j < NBINS / 256; ++j)
        blkhist[blk * NBINS + tid + j * 256] = hc[tid + j * 256];
}

__global__ __launch_bounds__(256) void k_scanA(int* __restrict__ blkhist,
                                               int* __restrict__ bintotal)
{
    int bin = blockIdx.x * 256 + threadIdx.x;   // 2048 threads
    int run = 0;
    for (int b = 0; b < NHB; ++b) {
        int v = blkhist[b * NBINS + bin];
        blkhist[b * NBINS + bin] = run;
        run += v;
    }
    bintotal[bin] = run;
}

__global__ __launch_bounds__(256) void k_scanB(const int* __restrict__ bintotal,
                                               int* __restrict__ binstart)
{
    int t = threadIdx.x;
    int v[8]; int sum = 0;
    #pragma unroll
    for (int j = 0; j < 8; ++j) { v[j] = bintotal[t * 8 + j]; sum += v[j]; }

    int lane = t & 63, w = t >> 6;
    int x = sum;
    #pragma unroll
    for (int d = 1; d < 64; d <<= 1) {
        int y = __shfl_up(x, d);
        if (lane >= d) x += y;
    }
    __shared__ int wsum[4];
    if (lane == 63) wsum[w] = x;
    __syncthreads();
    int woff = 0;
    for (int i = 0; i < w; ++i) woff += wsum[i];
    int run = woff + x - sum;
    #pragma unroll
    for (int j = 0; j < 8; ++j) { binstart[t * 8 + j] = run; run += v[j]; }
}

__global__ __launch_bounds__(256) void k_fill2(const float4* __restrict__ inp,
                                               const float* __restrict__ aabb,
                                               int N, int chunk,
                                               const int* __restrict__ blkhist,
                                               const int* __restrict__ binstart,
                                               int* __restrict__ order)
{
    __shared__ int hc[NBINS];
    const int tid = threadIdx.x, blk = blockIdx.x;
    #pragma unroll
    for (int j = 0; j < NBINS / 256; ++j) hc[tid + j * 256] = 0;
    __syncthreads();

    float a0x = aabb[0], a0y = aabb[1], a0z = aabb[2];
    float isx = 1.0f / (aabb[3] - a0x), isy = 1.0f / (aabb[4] - a0y), isz = 1.0f / (aabb[5] - a0z);

    int end = min(N, (blk + 1) * chunk);
    for (int i = blk * chunk + tid; i < end; i += 256) {
        int key = point_key(inp[i], a0x, a0y, a0z, isx, isy, isz);
        int lr  = atomicAdd(&hc[key], 1);
        order[binstart[key] + blkhist[blk * NBINS + key] + lr] = i;
    }
}

// ---------------------------------------------------------------------------
// Kernel 2: fused gather + MLP, 64 threads (1 wave) per 64 points.
// EXACT round-7 structure (532 us, 84 VGPR, wave-uniform w0/w1 scalar loads)
// + XCD-chunked block swizzle (the round-8 change that collapsed FETCH 5.3x).
// Phase A: 8 groups x 8 lanes; group g gathers points 8g..8g+7; lane k owns
//          feature block k. Per-plane bilinear fp16, cross-plane fp32.
// Phase B: thread-per-point MLP; w0/b0/w1 wave-uniform -> s_load.
// ---------------------------------------------------------------------------
DEVFN void corner4f(unsigned a, unsigned b, unsigned c, unsigned d,
                    __half2 w00, __half2 w01, __half2 w10, __half2 w11,
                    float& ax, float& ay)
{
    __half2 t = __hmul2(__builtin_bit_cast(__half2, a), w00);
    t = __hfma2(__builtin_bit_cast(__half2, b), w01, t);
    t = __hfma2(__builtin_bit_cast(__half2, c), w10, t);
    t = __hfma2(__builtin_bit_cast(__half2, d), w11, t);
    ax += __low2float(t);
    ay += __high2float(t);
}

__global__ __launch_bounds__(64) void k_main(
    const float4* __restrict__ inp,
    const float*  __restrict__ aabb,
    const __half* __restrict__ planes,
    const int*    __restrict__ order,
    int           useOrder,
    const float*  __restrict__ w0,
    const float*  __restrict__ b0,
    const float*  __restrict__ w1,
    const float*  __restrict__ b1,
    float*        __restrict__ out)
{
    __shared__ unsigned int lds[64 * 65];   // 64 pts x 64 feat-dwords, stride 65

    const int tid = threadIdx.x;
    const int g   = tid >> 3;
    const int k   = tid & 7;

    // XCD-chunked swizzle (bijective when nwg % 8 == 0): consecutive sorted
    // blocks land on the same XCD -> plane window cached once per XCD.
    const int nwg = gridDim.x;
    const int bid = blockIdx.x;
    const int wid = ((nwg & 7) == 0) ? ((bid & 7) * (nwg >> 3) + (bid >> 3)) : bid;
    const int base = wid * 64;

    // each thread owns the original index of "its" point (point p = tid)
    const int myord = useOrder ? order[base + tid] : (base + tid);

    float a0x = aabb[0], a0y = aabb[1], a0z = aabb[2];
    float sx  = aabb[3] - a0x, sy = aabb[4] - a0y, sz = aabb[5] - a0z;

    // ---------------- Phase A: gather ----------------
    for (int q = 0; q < 8; ++q) {
        const int p = g * 8 + q;
        const int pidx = __shfl(myord, p);       // original index of point p
        float4 in = inp[pidx];
        float c[4];
        c[0] = (in.x - a0x) / sx * 2.0f - 1.0f;
        c[1] = (in.y - a0y) / sy * 2.0f - 1.0f;
        c[2] = (in.z - a0z) / sz * 2.0f - 1.0f;
        c[3] = in.w * 2.0f - 1.0f;

        float accT[8], accS[8];
        #pragma unroll
        for (int j = 0; j < 8; ++j) { accT[j] = 0.0f; accS[j] = 0.0f; }

        #pragma unroll
        for (int pl = 0; pl < 9; ++pl) {
            const int W = 128;
            const int H = g_H[pl];
            float fx = (c[g_A[pl]] + 1.0f) * 0.5f * (float)(W - 1);
            float fy = (c[g_B[pl]] + 1.0f) * 0.5f * (float)(H - 1);
            int x0 = min(max((int)floorf(fx), 0), W - 2);
            int y0 = min(max((int)floorf(fy), 0), H - 2);
            float wx = fx - (float)x0;
            float wy = fy - (float)y0;
            float iwx = 1.0f - wx, iwy = 1.0f - wy;

            const uint4* pb = reinterpret_cast<const uint4*>(planes)
                            + g_OFF4[pl] + ((y0 << 7) + x0) * 8 + k;
            uint4 v00 = pb[0];
            uint4 v01 = pb[8];
            uint4 v10 = pb[1024];
            uint4 v11 = pb[1032];

            __half2 w00h = __float2half2_rn(iwx * iwy);
            __half2 w01h = __float2half2_rn(wx  * iwy);
            __half2 w10h = __float2half2_rn(iwx * wy);
            __half2 w11h = __float2half2_rn(wx  * wy);

            if (pl < 6) {
                corner4f(v00.x, v01.x, v10.x, v11.x, w00h, w01h, w10h, w11h, accT[0], accT[1]);
                corner4f(v00.y, v01.y, v10.y, v11.y, w00h, w01h, w10h, w11h, accT[2], accT[3]);
                corner4f(v00.z, v01.z, v10.z, v11.z, w00h, w01h, w10h, w11h, accT[4], accT[5]);
                corner4f(v00.w, v01.w, v10.w, v11.w, w00h, w01h, w10h, w11h, accT[6], accT[7]);
            } else {
                corner4f(v00.x, v01.x, v10.x, v11.x, w00h, w01h, w10h, w11h, accS[0], accS[1]);
                corner4f(v00.y, v01.y, v10.y, v11.y, w00h, w01h, w10h, w11h, accS[2], accS[3]);
                corner4f(v00.z, v01.z, v10.z, v11.z, w00h, w01h, w10h, w11h, accS[4], accS[5]);
                corner4f(v00.w, v01.w, v10.w, v11.w, w00h, w01h, w10h, w11h, accS[6], accS[7]);
            }
        }

        #pragma unroll
        for (int j = 0; j < 4; ++j) {
            lds[p * 65 +      k * 4 + j] =
                __builtin_bit_cast(unsigned int, __floats2half2_rn(accT[2*j], accT[2*j+1]));
            lds[p * 65 + 32 + k * 4 + j] =
                __builtin_bit_cast(unsigned int, __floats2half2_rn(accS[2*j], accS[2*j+1]));
        }
    }

    __syncthreads();

    // ---------------- Phase B: MLP (thread-per-point, wave-uniform weights) ----
    const unsigned int* lrow = &lds[tid * 65];
    float o0 = b1[0], o1 = b1[1], o2 = b1[2];

    #pragma unroll 1
    for (int jc = 0; jc < 64; jc += 16) {
        float h[16];
        #pragma unroll
        for (int jj = 0; jj < 16; ++jj) h[jj] = b0[jc + jj];

        #pragma unroll 4
        for (int d = 0; d < 64; ++d) {
            unsigned u = lrow[d];
            __half2 hv = __builtin_bit_cast(__half2, u);
            float f0 = __low2float(hv);
            float f1 = __high2float(hv);
            const float* wr = w0 + d * 128 + jc;   // w0 rows 2d and 2d+1 (row stride 64)
            #pragma unroll
            for (int jj = 0; jj < 16; ++jj) h[jj] = fmaf(f0, wr[jj], h[jj]);
            #pragma unroll
            for (int jj = 0; jj < 16; ++jj) h[jj] = fmaf(f1, wr[64 + jj], h[jj]);
        }

        #pragma unroll
        for (int jj = 0; jj < 16; ++jj) {
            float r = fmaxf(h[jj], 0.0f);
            const float* wq = w1 + (jc + jj) * 3;
            o0 = fmaf(r, wq[0], o0);
            o1 = fmaf(r, wq[1], o1);
            o2 = fmaf(r, wq[2], o2);
        }
    }

    long long oo = (long long)myord * 3;
    out[oo + 0] = o0;
    out[oo + 1] = o1;
    out[oo + 2] = o2;
}

// ---------------------------------------------------------------------------
// Fallback (d_ws too small or N not divisible by 64): slow but correct.
// ---------------------------------------------------------------------------
__global__ __launch_bounds__(256) void k_fallback(
    const float4* __restrict__ inp, const float* __restrict__ aabb, PlanePtrs ptrs,
    const float* __restrict__ w0, const float* __restrict__ b0,
    const float* __restrict__ w1, const float* __restrict__ b1,
    float* __restrict__ out, int N, int start)
{
    int pidx = start + blockIdx.x * 256 + threadIdx.x;
    if (pidx >= N) return;
    float4 in = inp[pidx];
    float c[4];
    c[0] = (in.x - aabb[0]) / (aabb[3] - aabb[0]) * 2.0f - 1.0f;
    c[1] = (in.y - aabb[1]) / (aabb[4] - aabb[1]) * 2.0f - 1.0f;
    c[2] = (in.z - aabb[2]) / (aabb[5] - aabb[2]) * 2.0f - 1.0f;
    c[3] = in.w * 2.0f - 1.0f;

    float h[64];
    #pragma unroll
    for (int j = 0; j < 64; ++j) h[j] = b0[j];

    #pragma unroll
    for (int pl = 0; pl < 9; ++pl) {
        const int W = 128, H = g_H[pl];
        float fx = (c[g_A[pl]] + 1.0f) * 0.5f * (float)(W - 1);
        float fy = (c[g_B[pl]] + 1.0f) * 0.5f * (float)(H - 1);
        int x0 = min(max((int)floorf(fx), 0), W - 2);
        int y0 = min(max((int)floorf(fy), 0), H - 2);
        float wx = fx - (float)x0, wy = fy - (float)y0;
        const float* P = ptrs.p[pl];
        int off = y0 * 128 + x0;
        int HW = H * 128;
        int row = (pl < 6) ? 0 : 64;
        for (int f = 0; f < 64; ++f) {
            const float* qp = P + f * HW + off;
            float v = (qp[0] * (1.0f - wx) + qp[1] * wx) * (1.0f - wy)
                    + (qp[128] * (1.0f - wx) + qp[129] * wx) * wy;
            const float* wr = w0 + (row + f) * 64;
            #pragma unroll
            for (int j = 0; j < 64; ++j) h[j] = fmaf(v, wr[j], h[j]);
        }
    }
    float o0 = b1[0], o1 = b1[1], o2 = b1[2];
    #pragma unroll
    for (int j = 0; j < 64; ++j) {
        float r = fmaxf(h[j], 0.0f);
        o0 = fmaf(r, w1[j * 3 + 0], o0);
        o1 = fmaf(r, w1[j * 3 + 1], o1);
        o2 = fmaf(r, w1[j * 3 + 2], o2);
    }
    out[(long long)pidx * 3 + 0] = o0;
    out[(long long)pidx * 3 + 1] = o1;
    out[(long long)pidx * 3 + 2] = o2;
}

// ---------------------------------------------------------------------------
extern "C" void kernel_launch(void* const* d_in, const int* in_sizes, int n_in,
                              void* d_out, int out_size, void* d_ws, size_t ws_size,
                              hipStream_t stream)
{
    const float4* inp  = (const float4*)d_in[0];
    const float*  aabb = (const float*)d_in[1];
    PlanePtrs ptrs;
    for (int i = 0; i < 9; ++i) ptrs.p[i] = (const float*)d_in[2 + i];
    const float* w0 = (const float*)d_in[11];
    const float* b0 = (const float*)d_in[12];
    const float* w1 = (const float*)d_in[13];
    const float* b1 = (const float*)d_in[14];
    float* out = (float*)d_out;
    const int N = in_sizes[0] / 4;

    const size_t off_order = WS_PLANES;
    const size_t off_bh    = off_order + 4ull * (size_t)N;
    const size_t off_bt    = off_bh + (size_t)NHB * NBINS * 4;
    const size_t off_bs    = off_bt + NBINS * 4;
    const size_t need_sort = off_bs + NBINS * 4;

    if (ws_size >= WS_PLANES && (N % 64) == 0) {
        __half* planes = (__half*)d_ws;
        k_transpose<<<TOTAL_TEXELS / 256, 256, 0, stream>>>(ptrs, planes);

        if (ws_size >= need_sort) {
            int* order    = (int*)((char*)d_ws + off_order);
            int* blkhist  = (int*)((char*)d_ws + off_bh);
            int* bintotal = (int*)((char*)d_ws + off_bt);
            int* binstart = (int*)((char*)d_ws + off_bs);
            int chunk = (((N + NHB - 1) / NHB) + 255) / 256 * 256;

            k_hist2<<<NHB, 256, 0, stream>>>(inp, aabb, N, chunk, blkhist);
            k_scanA<<<NBINS / 256, 256, 0, stream>>>(blkhist, bintotal);
            k_scanB<<<1, 256, 0, stream>>>(bintotal, binstart);
            k_fill2<<<NHB, 256, 0, stream>>>(inp, aabb, N, chunk, blkhist, binstart, order);
            k_main<<<N / 64, 64, 0, stream>>>(inp, aabb, planes, order, 1,
                                              w0, b0, w1, b1, out);
        } else {
            k_main<<<N / 64, 64, 0, stream>>>(inp, aabb, planes, (const int*)nullptr, 0,
                                              w0, b0, w1, b1, out);
        }
    } else {
        k_fallback<<<(N + 255) / 256, 256, 0, stream>>>(inp, aabb, ptrs, w0, b0, w1, b1, out, N, 0);
    }
}

// Round 10
// 363.453 us; speedup vs baseline: 3.0626x; 1.3393x over previous
//
#include <hip/hip_runtime.h>
#include <hip/hip_fp16.h>

#define DEVFN __device__ __forceinline__

#if defined(__has_builtin)
#  if __has_builtin(__builtin_amdgcn_fdot2)
#    define HAS_FDOT2 1
#  endif
#endif

typedef _Float16 h2v __attribute__((ext_vector_type(2)));

struct PlanePtrs { const float* p[9]; };

// Plane geometry (compile-time):
//   planes 0..5 temporal (tp0..tp5), 6..8 spatial (sp0..sp2)
//   W = 128 for all planes; H = 128 except planes 2,4,5 (H=100)
__constant__ const int g_H[9] = {128,128,100,128,100,100,128,128,128};
__constant__ const int g_A[9] = {0,0,0,1,1,2,0,0,1};
__constant__ const int g_B[9] = {1,2,3,2,3,3,1,2,2};
// absolute texel prefix boundaries (monotone -> order-safe plane select)
__constant__ const int g_PRE[10] = {0,16384,32768,45568,61952,74752,87552,103936,120320,136704};
// transposed-plane base offsets in uint4 units (= g_PRE[pl] * 8)
__constant__ const int g_OFF4[9] = {0,131072,262144,364544,495616,598016,700416,831488,962560};

static const int    TOTAL_TEXELS = 136704;            // g_PRE[9]
static const size_t WS_PLANES    = 17498112ull;       // fp16 planes bytes
static const size_t WS_W0H       = 16384ull;          // packed w0 fp16 pairs
static const int    NBINS        = 2048;
static const int    NHB          = 256;               // histogram blocks

// ---------------------------------------------------------------------------
// Kernel 1: transpose planes [64,H,W] f32 -> [H*W, 64] f16 (verified round 2)
// ---------------------------------------------------------------------------
__global__ __launch_bounds__(256) void k_transpose(PlanePtrs ptrs, __half* __restrict__ dst)
{
    int gid = blockIdx.x * 256 + threadIdx.x;

    int pl = 0;
    #pragma unroll
    for (int i = 1; i < 9; ++i) if (gid >= g_PRE[i]) pl = i;
    int tx   = gid - g_PRE[pl];
    int nTex = g_PRE[pl + 1] - g_PRE[pl];

    const float* src = ptrs.p[0];
    #pragma unroll
    for (int i = 1; i < 9; ++i) if (pl == i) src = ptrs.p[i];
    src += tx;

    uint4* __restrict__ out4 = reinterpret_cast<uint4*>(dst) + (size_t)gid * 8;
    #pragma unroll
    for (int j = 0; j < 8; ++j) {
        float f0 = src[(8*j+0)*nTex];
        float f1 = src[(8*j+1)*nTex];
        float f2 = src[(8*j+2)*nTex];
        float f3 = src[(8*j+3)*nTex];
        float f4 = src[(8*j+4)*nTex];
        float f5 = src[(8*j+5)*nTex];
        float f6 = src[(8*j+6)*nTex];
        float f7 = src[(8*j+7)*nTex];
        uint4 u;
        u.x = __builtin_bit_cast(unsigned int, __floats2half2_rn(f0, f1));
        u.y = __builtin_bit_cast(unsigned int, __floats2half2_rn(f2, f3));
        u.z = __builtin_bit_cast(unsigned int, __floats2half2_rn(f4, f5));
        u.w = __builtin_bit_cast(unsigned int, __floats2half2_rn(f6, f7));
        out4[j] = u;
    }
}

// ---------------------------------------------------------------------------
// Kernel 1b: pack w0 [128][64] f32 -> w0h[64][64] fp16 pairs:
//   w0h[d*64+j] = half2( w0[2d][j], w0[2d+1][j] )  — matches LDS feat pairs.
// ---------------------------------------------------------------------------
__global__ __launch_bounds__(256) void k_w0pack(const float* __restrict__ w0,
                                                unsigned int* __restrict__ w0h)
{
    int idx = blockIdx.x * 256 + threadIdx.x;     // 0..4095
    int d = idx >> 6, j = idx & 63;
    float a = w0[(2 * d) * 64 + j];
    float b = w0[(2 * d + 1) * 64 + j];
    w0h[idx] = __builtin_bit_cast(unsigned int, __floats2half2_rn(a, b));
}

// ---------------------------------------------------------------------------
// Sorting prepass (two-level, LDS atomics only) — verified round 8.
//   key = x:3 | y:3 | z:3 | t:2  (2048 bins)
// Index-only sort; output position/value depend only on the point itself
// -> deterministic output despite atomic rank ordering.
// ---------------------------------------------------------------------------
DEVFN int point_key(float4 in, float a0x, float a0y, float a0z,
                    float isx, float isy, float isz)
{
    float x = (in.x - a0x) * isx;
    float y = (in.y - a0y) * isy;
    float z = (in.z - a0z) * isz;
    int xc = min(7, max(0, (int)(x * 8.0f)));
    int yc = min(7, max(0, (int)(y * 8.0f)));
    int zc = min(7, max(0, (int)(z * 8.0f)));
    int tc = min(3, max(0, (int)(in.w * 4.0f)));
    return (((xc << 3) | yc) << 3 | zc) << 2 | tc;
}

__global__ __launch_bounds__(256) void k_hist2(const float4* __restrict__ inp,
                                               const float* __restrict__ aabb,
                                               int N, int chunk,
                                               int* __restrict__ blkhist)
{
    __shared__ int hc[NBINS];
    const int tid = threadIdx.x, blk = blockIdx.x;
    #pragma unroll
    for (int j = 0; j < NBINS / 256; ++j) hc[tid + j * 256] = 0;
    __syncthreads();

    float a0x = aabb[0], a0y = aabb[1], a0z = aabb[2];
    float isx = 1.0f / (aabb[3] - a0x), isy = 1.0f / (aabb[4] - a0y), isz = 1.0f / (aabb[5] - a0z);

    int end = min(N, (blk + 1) * chunk);
    for (int i = blk * chunk + tid; i < end; i += 256)
        atomicAdd(&hc[point_key(inp[i], a0x, a0y, a0z, isx, isy, isz)], 1);

    __syncthreads();
    #pragma unroll
    for (int j = 0; j < NBINS / 256; ++j)
        blkhist[blk * NBINS + tid + j * 256] = hc[tid + j * 256];
}

__global__ __launch_bounds__(256) void k_scanA(int* __restrict__ blkhist,
                                               int* __restrict__ bintotal)
{
    int bin = blockIdx.x * 256 + threadIdx.x;   // 2048 threads
    int run = 0;
    for (int b = 0; b < NHB; ++b) {
        int v = blkhist[b * NBINS + bin];
        blkhist[b * NBINS + bin] = run;
        run += v;
    }
    bintotal[bin] = run;
}

__global__ __launch_bounds__(256) void k_scanB(const int* __restrict__ bintotal,
                                               int* __restrict__ binstart)
{
    int t = threadIdx.x;
    int v[8]; int sum = 0;
    #pragma unroll
    for (int j = 0; j < 8; ++j) { v[j] = bintotal[t * 8 + j]; sum += v[j]; }

    int lane = t & 63, w = t >> 6;
    int x = sum;
    #pragma unroll
    for (int d = 1; d < 64; d <<= 1) {
        int y = __shfl_up(x, d);
        if (lane >= d) x += y;
    }
    __shared__ int wsum[4];
    if (lane == 63) wsum[w] = x;
    __syncthreads();
    int woff = 0;
    for (int i = 0; i < w; ++i) woff += wsum[i];
    int run = woff + x - sum;
    #pragma unroll
    for (int j = 0; j < 8; ++j) { binstart[t * 8 + j] = run; run += v[j]; }
}

__global__ __launch_bounds__(256) void k_fill2(const float4* __restrict__ inp,
                                               const float* __restrict__ aabb,
                                               int N, int chunk,
                                               const int* __restrict__ blkhist,
                                               const int* __restrict__ binstart,
                                               int* __restrict__ order)
{
    __shared__ int hc[NBINS];
    const int tid = threadIdx.x, blk = blockIdx.x;
    #pragma unroll
    for (int j = 0; j < NBINS / 256; ++j) hc[tid + j * 256] = 0;
    __syncthreads();

    float a0x = aabb[0], a0y = aabb[1], a0z = aabb[2];
    float isx = 1.0f / (aabb[3] - a0x), isy = 1.0f / (aabb[4] - a0y), isz = 1.0f / (aabb[5] - a0z);

    int end = min(N, (blk + 1) * chunk);
    for (int i = blk * chunk + tid; i < end; i += 256) {
        int key = point_key(inp[i], a0x, a0y, a0z, isx, isy, isz);
        int lr  = atomicAdd(&hc[key], 1);
        order[binstart[key] + blkhist[blk * NBINS + key] + lr] = i;
    }
}

// ---------------------------------------------------------------------------
// Kernel 2: fused gather + MLP, 64 threads (1 wave) per 64 points.
// Round-9 structure (sort + XCD swizzle + wave-uniform MLP) with the layer-1
// inner product switched to v_dot2_f32_f16 (2 fp16 MACs / instr, fp32 acc)
// against pre-packed w0h. Halves phase-B VALU instruction count.
// ---------------------------------------------------------------------------
DEVFN void corner4f(unsigned a, unsigned b, unsigned c, unsigned d,
                    __half2 w00, __half2 w01, __half2 w10, __half2 w11,
                    float& ax, float& ay)
{
    __half2 t = __hmul2(__builtin_bit_cast(__half2, a), w00);
    t = __hfma2(__builtin_bit_cast(__half2, b), w01, t);
    t = __hfma2(__builtin_bit_cast(__half2, c), w10, t);
    t = __hfma2(__builtin_bit_cast(__half2, d), w11, t);
    ax += __low2float(t);
    ay += __high2float(t);
}

__global__ __launch_bounds__(64) void k_main(
    const float4* __restrict__ inp,
    const float*  __restrict__ aabb,
    const __half* __restrict__ planes,
    const unsigned int* __restrict__ w0h,
    const int*    __restrict__ order,
    int           useOrder,
    const float*  __restrict__ w0,
    const float*  __restrict__ b0,
    const float*  __restrict__ w1,
    const float*  __restrict__ b1,
    float*        __restrict__ out)
{
    __shared__ unsigned int lds[64 * 65];   // 64 pts x 64 feat-dwords, stride 65

    const int tid = threadIdx.x;
    const int g   = tid >> 3;
    const int k   = tid & 7;

    // XCD-chunked swizzle (bijective when nwg % 8 == 0): consecutive sorted
    // blocks land on the same XCD -> plane window cached once per XCD.
    const int nwg = gridDim.x;
    const int bid = blockIdx.x;
    const int wid = ((nwg & 7) == 0) ? ((bid & 7) * (nwg >> 3) + (bid >> 3)) : bid;
    const int base = wid * 64;

    // each thread owns the original index of "its" point (point p = tid)
    const int myord = useOrder ? order[base + tid] : (base + tid);

    float a0x = aabb[0], a0y = aabb[1], a0z = aabb[2];
    float sx  = aabb[3] - a0x, sy = aabb[4] - a0y, sz = aabb[5] - a0z;

    // ---------------- Phase A: gather ----------------
    for (int q = 0; q < 8; ++q) {
        const int p = g * 8 + q;
        const int pidx = __shfl(myord, p);       // original index of point p
        float4 in = inp[pidx];
        float c[4];
        c[0] = (in.x - a0x) / sx * 2.0f - 1.0f;
        c[1] = (in.y - a0y) / sy * 2.0f - 1.0f;
        c[2] = (in.z - a0z) / sz * 2.0f - 1.0f;
        c[3] = in.w * 2.0f - 1.0f;

        float accT[8], accS[8];
        #pragma unroll
        for (int j = 0; j < 8; ++j) { accT[j] = 0.0f; accS[j] = 0.0f; }

        #pragma unroll
        for (int pl = 0; pl < 9; ++pl) {
            const int W = 128;
            const int H = g_H[pl];
            float fx = (c[g_A[pl]] + 1.0f) * 0.5f * (float)(W - 1);
            float fy = (c[g_B[pl]] + 1.0f) * 0.5f * (float)(H - 1);
            int x0 = min(max((int)floorf(fx), 0), W - 2);
            int y0 = min(max((int)floorf(fy), 0), H - 2);
            float wx = fx - (float)x0;
            float wy = fy - (float)y0;
            float iwx = 1.0f - wx, iwy = 1.0f - wy;

            const uint4* pb = reinterpret_cast<const uint4*>(planes)
                            + g_OFF4[pl] + ((y0 << 7) + x0) * 8 + k;
            uint4 v00 = pb[0];
            uint4 v01 = pb[8];
            uint4 v10 = pb[1024];
            uint4 v11 = pb[1032];

            __half2 w00h = __float2half2_rn(iwx * iwy);
            __half2 w01h = __float2half2_rn(wx  * iwy);
            __half2 w10h = __float2half2_rn(iwx * wy);
            __half2 w11h = __float2half2_rn(wx  * wy);

            if (pl < 6) {
                corner4f(v00.x, v01.x, v10.x, v11.x, w00h, w01h, w10h, w11h, accT[0], accT[1]);
                corner4f(v00.y, v01.y, v10.y, v11.y, w00h, w01h, w10h, w11h, accT[2], accT[3]);
                corner4f(v00.z, v01.z, v10.z, v11.z, w00h, w01h, w10h, w11h, accT[4], accT[5]);
                corner4f(v00.w, v01.w, v10.w, v11.w, w00h, w01h, w10h, w11h, accT[6], accT[7]);
            } else {
                corner4f(v00.x, v01.x, v10.x, v11.x, w00h, w01h, w10h, w11h, accS[0], accS[1]);
                corner4f(v00.y, v01.y, v10.y, v11.y, w00h, w01h, w10h, w11h, accS[2], accS[3]);
                corner4f(v00.z, v01.z, v10.z, v11.z, w00h, w01h, w10h, w11h, accS[4], accS[5]);
                corner4f(v00.w, v01.w, v10.w, v11.w, w00h, w01h, w10h, w11h, accS[6], accS[7]);
            }
        }

        #pragma unroll
        for (int j = 0; j < 4; ++j) {
            lds[p * 65 +      k * 4 + j] =
                __builtin_bit_cast(unsigned int, __floats2half2_rn(accT[2*j], accT[2*j+1]));
            lds[p * 65 + 32 + k * 4 + j] =
                __builtin_bit_cast(unsigned int, __floats2half2_rn(accS[2*j], accS[2*j+1]));
        }
    }

    __syncthreads();

    // ------- Phase B: MLP (thread-per-point, wave-uniform weights) -------
    const unsigned int* lrow = &lds[tid * 65];
    float o0 = b1[0], o1 = b1[1], o2 = b1[2];

    #pragma unroll 1
    for (int jc = 0; jc < 64; jc += 16) {
        float h[16];
        #pragma unroll
        for (int jj = 0; jj < 16; ++jj) h[jj] = b0[jc + jj];

        #pragma unroll 4
        for (int d = 0; d < 64; ++d) {
            unsigned u = lrow[d];                 // fp16 pair: feats (2d, 2d+1)
#if defined(HAS_FDOT2)
            h2v fv = __builtin_bit_cast(h2v, u);
            const unsigned int* wr = w0h + d * 64 + jc;   // wave-uniform -> s_load
            #pragma unroll
            for (int jj = 0; jj < 16; ++jj)
                h[jj] = __builtin_amdgcn_fdot2(fv, __builtin_bit_cast(h2v, wr[jj]),
                                               h[jj], false);
#else
            __half2 hv = __builtin_bit_cast(__half2, u);
            float f0 = __low2float(hv);
            float f1 = __high2float(hv);
            const float* wr = w0 + d * 128 + jc;  // w0 rows 2d, 2d+1 (stride 64)
            #pragma unroll
            for (int jj = 0; jj < 16; ++jj) h[jj] = fmaf(f0, wr[jj], h[jj]);
            #pragma unroll
            for (int jj = 0; jj < 16; ++jj) h[jj] = fmaf(f1, wr[64 + jj], h[jj]);
#endif
        }

        #pragma unroll
        for (int jj = 0; jj < 16; ++jj) {
            float r = fmaxf(h[jj], 0.0f);
            const float* wq = w1 + (jc + jj) * 3;
            o0 = fmaf(r, wq[0], o0);
            o1 = fmaf(r, wq[1], o1);
            o2 = fmaf(r, wq[2], o2);
        }
    }

    long long oo = (long long)myord * 3;
    out[oo + 0] = o0;
    out[oo + 1] = o1;
    out[oo + 2] = o2;
}

// ---------------------------------------------------------------------------
// Fallback (d_ws too small or N not divisible by 64): slow but correct.
// ---------------------------------------------------------------------------
__global__ __launch_bounds__(256) void k_fallback(
    const float4* __restrict__ inp, const float* __restrict__ aabb, PlanePtrs ptrs,
    const float* __restrict__ w0, const float* __restrict__ b0,
    const float* __restrict__ w1, const float* __restrict__ b1,
    float* __restrict__ out, int N, int start)
{
    int pidx = start + blockIdx.x * 256 + threadIdx.x;
    if (pidx >= N) return;
    float4 in = inp[pidx];
    float c[4];
    c[0] = (in.x - aabb[0]) / (aabb[3] - aabb[0]) * 2.0f - 1.0f;
    c[1] = (in.y - aabb[1]) / (aabb[4] - aabb[1]) * 2.0f - 1.0f;
    c[2] = (in.z - aabb[2]) / (aabb[5] - aabb[2]) * 2.0f - 1.0f;
    c[3] = in.w * 2.0f - 1.0f;

    float h[64];
    #pragma unroll
    for (int j = 0; j < 64; ++j) h[j] = b0[j];

    #pragma unroll
    for (int pl = 0; pl < 9; ++pl) {
        const int W = 128, H = g_H[pl];
        float fx = (c[g_A[pl]] + 1.0f) * 0.5f * (float)(W - 1);
        float fy = (c[g_B[pl]] + 1.0f) * 0.5f * (float)(H - 1);
        int x0 = min(max((int)floorf(fx), 0), W - 2);
        int y0 = min(max((int)floorf(fy), 0), H - 2);
        float wx = fx - (float)x0, wy = fy - (float)y0;
        const float* P = ptrs.p[pl];
        int off = y0 * 128 + x0;
        int HW = H * 128;
        int row = (pl < 6) ? 0 : 64;
        for (int f = 0; f < 64; ++f) {
            const float* qp = P + f * HW + off;
            float v = (qp[0] * (1.0f - wx) + qp[1] * wx) * (1.0f - wy)
                    + (qp[128] * (1.0f - wx) + qp[129] * wx) * wy;
            const float* wr = w0 + (row + f) * 64;
            #pragma unroll
            for (int j = 0; j < 64; ++j) h[j] = fmaf(v, wr[j], h[j]);
        }
    }
    float o0 = b1[0], o1 = b1[1], o2 = b1[2];
    #pragma unroll
    for (int j = 0; j < 64; ++j) {
        float r = fmaxf(h[j], 0.0f);
        o0 = fmaf(r, w1[j * 3 + 0], o0);
        o1 = fmaf(r, w1[j * 3 + 1], o1);
        o2 = fmaf(r, w1[j * 3 + 2], o2);
    }
    out[(long long)pidx * 3 + 0] = o0;
    out[(long long)pidx * 3 + 1] = o1;
    out[(long long)pidx * 3 + 2] = o2;
}

// ---------------------------------------------------------------------------
extern "C" void kernel_launch(void* const* d_in, const int* in_sizes, int n_in,
                              void* d_out, int out_size, void* d_ws, size_t ws_size,
                              hipStream_t stream)
{
    const float4* inp  = (const float4*)d_in[0];
    const float*  aabb = (const float*)d_in[1];
    PlanePtrs ptrs;
    for (int i = 0; i < 9; ++i) ptrs.p[i] = (const float*)d_in[2 + i];
    const float* w0 = (const float*)d_in[11];
    const float* b0 = (const float*)d_in[12];
    const float* w1 = (const float*)d_in[13];
    const float* b1 = (const float*)d_in[14];
    float* out = (float*)d_out;
    const int N = in_sizes[0] / 4;

    const size_t off_w0h   = WS_PLANES;
    const size_t ws_base   = WS_PLANES + WS_W0H;
    const size_t off_order = ws_base;
    const size_t off_bh    = off_order + 4ull * (size_t)N;
    const size_t off_bt    = off_bh + (size_t)NHB * NBINS * 4;
    const size_t off_bs    = off_bt + NBINS * 4;
    const size_t need_sort = off_bs + NBINS * 4;

    if (ws_size >= ws_base && (N % 64) == 0) {
        __half* planes = (__half*)d_ws;
        unsigned int* w0h = (unsigned int*)((char*)d_ws + off_w0h);
        k_transpose<<<TOTAL_TEXELS / 256, 256, 0, stream>>>(ptrs, planes);
        k_w0pack<<<16, 256, 0, stream>>>(w0, w0h);

        if (ws_size >= need_sort) {
            int* order    = (int*)((char*)d_ws + off_order);
            int* blkhist  = (int*)((char*)d_ws + off_bh);
            int* bintotal = (int*)((char*)d_ws + off_bt);
            int* binstart = (int*)((char*)d_ws + off_bs);
            int chunk = (((N + NHB - 1) / NHB) + 255) / 256 * 256;

            k_hist2<<<NHB, 256, 0, stream>>>(inp, aabb, N, chunk, blkhist);
            k_scanA<<<NBINS / 256, 256, 0, stream>>>(blkhist, bintotal);
            k_scanB<<<1, 256, 0, stream>>>(bintotal, binstart);
            k_fill2<<<NHB, 256, 0, stream>>>(inp, aabb, N, chunk, blkhist, binstart, order);
            k_main<<<N / 64, 64, 0, stream>>>(inp, aabb, planes, w0h, order, 1,
                                              w0, b0, w1, b1, out);
        } else {
            k_main<<<N / 64, 64, 0, stream>>>(inp, aabb, planes, w0h, (const int*)nullptr, 0,
                                              w0, b0, w1, b1, out);
        }
    } else {
        k_fallback<<<(N + 255) / 256, 256, 0, stream>>>(inp, aabb, ptrs, w0, b0, w1, b1, out, N, 0);
    }
}

// Round 13
// 347.887 us; speedup vs baseline: 3.1996x; 1.0447x over previous
//
#include <hip/hip_runtime.h>
#include <hip/hip_fp16.h>

#define DEVFN __device__ __forceinline__

#if defined(__has_builtin)
#  if __has_builtin(__builtin_amdgcn_fdot2)
#    define HAS_FDOT2 1
#  endif
#endif

typedef _Float16 h2v __attribute__((ext_vector_type(2)));

struct PlanePtrs { const float* p[9]; };

// Plane geometry (compile-time):
//   planes 0..5 temporal (tp0..tp5), 6..8 spatial (sp0..sp2)
//   W = 128 for all planes; H = 128 except planes 2,4,5 (H=100)
__constant__ const int g_H[9] = {128,128,100,128,100,100,128,128,128};
__constant__ const int g_A[9] = {0,0,0,1,1,2,0,0,1};
__constant__ const int g_B[9] = {1,2,3,2,3,3,1,2,2};
// absolute texel prefix boundaries (monotone -> order-safe plane select)
__constant__ const int g_PRE[10] = {0,16384,32768,45568,61952,74752,87552,103936,120320,136704};
// transposed-plane base offsets in uint4 units (= g_PRE[pl] * 8)
__constant__ const int g_OFF4[9] = {0,131072,262144,364544,495616,598016,700416,831488,962560};

static const int    TOTAL_TEXELS = 136704;            // g_PRE[9]
static const size_t WS_PLANES    = 17498112ull;       // fp16 planes bytes
static const size_t WS_W0H       = 16384ull;          // packed w0 fp16 pairs
static const int    NBINS        = 2048;
static const int    NHB          = 256;               // histogram blocks

// ---------------------------------------------------------------------------
// Kernel 1: transpose planes [64,H,W] f32 -> [H*W, 64] f16 (verified round 2)
// ---------------------------------------------------------------------------
__global__ __launch_bounds__(256) void k_transpose(PlanePtrs ptrs, __half* __restrict__ dst)
{
    int gid = blockIdx.x * 256 + threadIdx.x;

    int pl = 0;
    #pragma unroll
    for (int i = 1; i < 9; ++i) if (gid >= g_PRE[i]) pl = i;
    int tx   = gid - g_PRE[pl];
    int nTex = g_PRE[pl + 1] - g_PRE[pl];

    const float* src = ptrs.p[0];
    #pragma unroll
    for (int i = 1; i < 9; ++i) if (pl == i) src = ptrs.p[i];
    src += tx;

    uint4* __restrict__ out4 = reinterpret_cast<uint4*>(dst) + (size_t)gid * 8;
    #pragma unroll
    for (int j = 0; j < 8; ++j) {
        float f0 = src[(8*j+0)*nTex];
        float f1 = src[(8*j+1)*nTex];
        float f2 = src[(8*j+2)*nTex];
        float f3 = src[(8*j+3)*nTex];
        float f4 = src[(8*j+4)*nTex];
        float f5 = src[(8*j+5)*nTex];
        float f6 = src[(8*j+6)*nTex];
        float f7 = src[(8*j+7)*nTex];
        uint4 u;
        u.x = __builtin_bit_cast(unsigned int, __floats2half2_rn(f0, f1));
        u.y = __builtin_bit_cast(unsigned int, __floats2half2_rn(f2, f3));
        u.z = __builtin_bit_cast(unsigned int, __floats2half2_rn(f4, f5));
        u.w = __builtin_bit_cast(unsigned int, __floats2half2_rn(f6, f7));
        out4[j] = u;
    }
}

// ---------------------------------------------------------------------------
// Kernel 1b: pack w0 [128][64] f32 -> w0h[64][64] fp16 pairs (verified r10):
//   w0h[d*64+j] = half2( w0[2d][j], w0[2d+1][j] )  — matches LDS feat pairs.
// ---------------------------------------------------------------------------
__global__ __launch_bounds__(256) void k_w0pack(const float* __restrict__ w0,
                                                unsigned int* __restrict__ w0h)
{
    int idx = blockIdx.x * 256 + threadIdx.x;     // 0..4095
    int d = idx >> 6, j = idx & 63;
    float a = w0[(2 * d) * 64 + j];
    float b = w0[(2 * d + 1) * 64 + j];
    w0h[idx] = __builtin_bit_cast(unsigned int, __floats2half2_rn(a, b));
}

// ---------------------------------------------------------------------------
// Sorting prepass (two-level, LDS atomics only) — verified round 8.
// ---------------------------------------------------------------------------
DEVFN int point_key(float4 in, float a0x, float a0y, float a0z,
                    float isx, float isy, float isz)
{
    float x = (in.x - a0x) * isx;
    float y = (in.y - a0y) * isy;
    float z = (in.z - a0z) * isz;
    int xc = min(7, max(0, (int)(x * 8.0f)));
    int yc = min(7, max(0, (int)(y * 8.0f)));
    int zc = min(7, max(0, (int)(z * 8.0f)));
    int tc = min(3, max(0, (int)(in.w * 4.0f)));
    return (((xc << 3) | yc) << 3 | zc) << 2 | tc;
}

__global__ __launch_bounds__(256) void k_hist2(const float4* __restrict__ inp,
                                               const float* __restrict__ aabb,
                                               int N, int chunk,
                                               int* __restrict__ blkhist)
{
    __shared__ int hc[NBINS];
    const int tid = threadIdx.x, blk = blockIdx.x;
    #pragma unroll
    for (int j = 0; j < NBINS / 256; ++j) hc[tid + j * 256] = 0;
    __syncthreads();

    float a0x = aabb[0], a0y = aabb[1], a0z = aabb[2];
    float isx = 1.0f / (aabb[3] - a0x), isy = 1.0f / (aabb[4] - a0y), isz = 1.0f / (aabb[5] - a0z);

    int end = min(N, (blk + 1) * chunk);
    for (int i = blk * chunk + tid; i < end; i += 256)
        atomicAdd(&hc[point_key(inp[i], a0x, a0y, a0z, isx, isy, isz)], 1);

    __syncthreads();
    #pragma unroll
    for (int j = 0; j < NBINS / 256; ++j)
        blkhist[blk * NBINS + tid + j * 256] = hc[tid + j * 256];
}

__global__ __launch_bounds__(256) void k_scanA(int* __restrict__ blkhist,
                                               int* __restrict__ bintotal)
{
    int bin = blockIdx.x * 256 + threadIdx.x;   // 2048 threads
    int run = 0;
    for (int b = 0; b < NHB; ++b) {
        int v = blkhist[b * NBINS + bin];
        blkhist[b * NBINS + bin] = run;
        run += v;
    }
    bintotal[bin] = run;
}

__global__ __launch_bounds__(256) void k_scanB(const int* __restrict__ bintotal,
                                               int* __restrict__ binstart)
{
    int t = threadIdx.x;
    int v[8]; int sum = 0;
    #pragma unroll
    for (int j = 0; j < 8; ++j) { v[j] = bintotal[t * 8 + j]; sum += v[j]; }

    int lane = t & 63, w = t >> 6;
    int x = sum;
    #pragma unroll
    for (int d = 1; d < 64; d <<= 1) {
        int y = __shfl_up(x, d);
        if (lane >= d) x += y;
    }
    __shared__ int wsum[4];
    if (lane == 63) wsum[w] = x;
    __syncthreads();
    int woff = 0;
    for (int i = 0; i < w; ++i) woff += wsum[i];
    int run = woff + x - sum;
    #pragma unroll
    for (int j = 0; j < 8; ++j) { binstart[t * 8 + j] = run; run += v[j]; }
}

__global__ __launch_bounds__(256) void k_fill2(const float4* __restrict__ inp,
                                               const float* __restrict__ aabb,
                                               int N, int chunk,
                                               const int* __restrict__ blkhist,
                                               const int* __restrict__ binstart,
                                               int* __restrict__ order)
{
    __shared__ int hc[NBINS];
    const int tid = threadIdx.x, blk = blockIdx.x;
    #pragma unroll
    for (int j = 0; j < NBINS / 256; ++j) hc[tid + j * 256] = 0;
    __syncthreads();

    float a0x = aabb[0], a0y = aabb[1], a0z = aabb[2];
    float isx = 1.0f / (aabb[3] - a0x), isy = 1.0f / (aabb[4] - a0y), isz = 1.0f / (aabb[5] - a0z);

    int end = min(N, (blk + 1) * chunk);
    for (int i = blk * chunk + tid; i < end; i += 256) {
        int key = point_key(inp[i], a0x, a0y, a0z, isx, isy, isz);
        int lr  = atomicAdd(&hc[key], 1);
        order[binstart[key] + blkhist[blk * NBINS + key] + lr] = i;
    }
}

// ---------------------------------------------------------------------------
// Kernel 2: fused gather + MLP, 64 threads (1 wave) per 64 points.
// Round-10 verified structure (sort + XCD swizzle + fdot2 MLP) with phase A
// restructured for latency hiding at fixed (LDS-capped) occupancy:
//   - per-thread inp load once; coords distributed via __shfl
//   - all 9 planes' addresses + bilinear weights hoisted before any load
//   - explicit 4-deep texel-load pipeline (16 uint4 in flight)
// ---------------------------------------------------------------------------
DEVFN void corner4f(unsigned a, unsigned b, unsigned c, unsigned d,
                    __half2 w00, __half2 w01, __half2 w10, __half2 w11,
                    float& ax, float& ay)
{
    __half2 t = __hmul2(__builtin_bit_cast(__half2, a), w00);
    t = __hfma2(__builtin_bit_cast(__half2, b), w01, t);
    t = __hfma2(__builtin_bit_cast(__half2, c), w10, t);
    t = __hfma2(__builtin_bit_cast(__half2, d), w11, t);
    ax += __low2float(t);
    ay += __high2float(t);
}

__global__ __launch_bounds__(64) void k_main(
    const float4* __restrict__ inp,
    const float*  __restrict__ aabb,
    const __half* __restrict__ planes,
    const unsigned int* __restrict__ w0h,
    const int*    __restrict__ order,
    int           useOrder,
    const float*  __restrict__ w0,
    const float*  __restrict__ b0,
    const float*  __restrict__ w1,
    const float*  __restrict__ b1,
    float*        __restrict__ out)
{
    __shared__ unsigned int lds[64 * 65];   // 64 pts x 64 feat-dwords, stride 65

    const int tid = threadIdx.x;
    const int g   = tid >> 3;
    const int k   = tid & 7;

    // XCD-chunked swizzle (bijective when nwg % 8 == 0)
    const int nwg = gridDim.x;
    const int bid = blockIdx.x;
    const int wid = ((nwg & 7) == 0) ? ((bid & 7) * (nwg >> 3) + (bid >> 3)) : bid;
    const int base = wid * 64;

    // each thread owns the original index of "its" point (point p = tid)
    const int myord = useOrder ? order[base + tid] : (base + tid);

    float a0x = aabb[0], a0y = aabb[1], a0z = aabb[2];
    float sx  = aabb[3] - a0x, sy = aabb[4] - a0y, sz = aabb[5] - a0z;

    // normalized coords for THIS thread's point (loaded once; shfl'd below)
    float4 min_ = inp[myord];
    float c0 = (min_.x - a0x) / sx * 2.0f - 1.0f;
    float c1 = (min_.y - a0y) / sy * 2.0f - 1.0f;
    float c2 = (min_.z - a0z) / sz * 2.0f - 1.0f;
    float c3 = min_.w * 2.0f - 1.0f;

    const uint4* pbase = reinterpret_cast<const uint4*>(planes);

    // ---------------- Phase A: gather (4-deep load pipeline) ----------------
    #pragma unroll 1
    for (int q = 0; q < 8; ++q) {
        const int p = g * 8 + q;
        float cc[4];
        cc[0] = __shfl(c0, p);
        cc[1] = __shfl(c1, p);
        cc[2] = __shfl(c2, p);
        cc[3] = __shfl(c3, p);

        // hoist all 9 planes' addresses + packed weights
        int     offv[9];
        __half2 Wv[9][4];
        #pragma unroll
        for (int pl = 0; pl < 9; ++pl) {
            const int W = 128;
            const int H = g_H[pl];
            float fx = (cc[g_A[pl]] + 1.0f) * 0.5f * (float)(W - 1);
            float fy = (cc[g_B[pl]] + 1.0f) * 0.5f * (float)(H - 1);
            int x0 = min(max((int)floorf(fx), 0), W - 2);
            int y0 = min(max((int)floorf(fy), 0), H - 2);
            float wx = fx - (float)x0;
            float wy = fy - (float)y0;
            float iwx = 1.0f - wx, iwy = 1.0f - wy;
            offv[pl]  = g_OFF4[pl] + ((y0 << 7) + x0) * 8 + k;
            Wv[pl][0] = __float2half2_rn(iwx * iwy);
            Wv[pl][1] = __float2half2_rn(wx  * iwy);
            Wv[pl][2] = __float2half2_rn(iwx * wy);
            Wv[pl][3] = __float2half2_rn(wx  * wy);
        }

        // prologue: prefetch planes 0..3 (16 uint4 in flight)
        uint4 v00[4], v01[4], v10[4], v11[4];
        #pragma unroll
        for (int s = 0; s < 4; ++s) {
            const uint4* pb = pbase + offv[s];
            v00[s] = pb[0];
            v01[s] = pb[8];
            v10[s] = pb[1024];
            v11[s] = pb[1032];
        }

        float accT[8], accS[8];
        #pragma unroll
        for (int j = 0; j < 8; ++j) { accT[j] = 0.0f; accS[j] = 0.0f; }

        #pragma unroll
        for (int pl = 0; pl < 9; ++pl) {
            const int s = pl & 3;
            if (pl < 6) {
                corner4f(v00[s].x, v01[s].x, v10[s].x, v11[s].x,
                         Wv[pl][0], Wv[pl][1], Wv[pl][2], Wv[pl][3], accT[0], accT[1]);
                corner4f(v00[s].y, v01[s].y, v10[s].y, v11[s].y,
                         Wv[pl][0], Wv[pl][1], Wv[pl][2], Wv[pl][3], accT[2], accT[3]);
                corner4f(v00[s].z, v01[s].z, v10[s].z, v11[s].z,
                         Wv[pl][0], Wv[pl][1], Wv[pl][2], Wv[pl][3], accT[4], accT[5]);
                corner4f(v00[s].w, v01[s].w, v10[s].w, v11[s].w,
                         Wv[pl][0], Wv[pl][1], Wv[pl][2], Wv[pl][3], accT[6], accT[7]);
            } else {
                corner4f(v00[s].x, v01[s].x, v10[s].x, v11[s].x,
                         Wv[pl][0], Wv[pl][1], Wv[pl][2], Wv[pl][3], accS[0], accS[1]);
                corner4f(v00[s].y, v01[s].y, v10[s].y, v11[s].y,
                         Wv[pl][0], Wv[pl][1], Wv[pl][2], Wv[pl][3], accS[2], accS[3]);
                corner4f(v00[s].z, v01[s].z, v10[s].z, v11[s].z,
                         Wv[pl][0], Wv[pl][1], Wv[pl][2], Wv[pl][3], accS[4], accS[5]);
                corner4f(v00[s].w, v01[s].w, v10[s].w, v11[s].w,
                         Wv[pl][0], Wv[pl][1], Wv[pl][2], Wv[pl][3], accS[6], accS[7]);
            }
            if (pl + 4 < 9) {               // reload the slot just consumed
                const uint4* pb = pbase + offv[pl + 4];
                v00[s] = pb[0];
                v01[s] = pb[8];
                v10[s] = pb[1024];
                v11[s] = pb[1032];
            }
        }

        #pragma unroll
        for (int j = 0; j < 4; ++j) {
            lds[p * 65 +      k * 4 + j] =
                __builtin_bit_cast(unsigned int, __floats2half2_rn(accT[2*j], accT[2*j+1]));
            lds[p * 65 + 32 + k * 4 + j] =
                __builtin_bit_cast(unsigned int, __floats2half2_rn(accS[2*j], accS[2*j+1]));
        }
    }

    __syncthreads();

    // ------- Phase B: MLP (thread-per-point, wave-uniform weights; r10) -------
    const unsigned int* lrow = &lds[tid * 65];
    float o0 = b1[0], o1 = b1[1], o2 = b1[2];

    #pragma unroll 1
    for (int jc = 0; jc < 64; jc += 16) {
        float h[16];
        #pragma unroll
        for (int jj = 0; jj < 16; ++jj) h[jj] = b0[jc + jj];

        #pragma unroll 4
        for (int d = 0; d < 64; ++d) {
            unsigned u = lrow[d];                 // fp16 pair: feats (2d, 2d+1)
#if defined(HAS_FDOT2)
            h2v fv = __builtin_bit_cast(h2v, u);
            const unsigned int* wr = w0h + d * 64 + jc;   // wave-uniform -> s_load
            #pragma unroll
            for (int jj = 0; jj < 16; ++jj)
                h[jj] = __builtin_amdgcn_fdot2(fv, __builtin_bit_cast(h2v, wr[jj]),
                                               h[jj], false);
#else
            __half2 hv = __builtin_bit_cast(__half2, u);
            float f0 = __low2float(hv);
            float f1 = __high2float(hv);
            const float* wr = w0 + d * 128 + jc;  // w0 rows 2d, 2d+1 (stride 64)
            #pragma unroll
            for (int jj = 0; jj < 16; ++jj) h[jj] = fmaf(f0, wr[jj], h[jj]);
            #pragma unroll
            for (int jj = 0; jj < 16; ++jj) h[jj] = fmaf(f1, wr[64 + jj], h[jj]);
#endif
        }

        #pragma unroll
        for (int jj = 0; jj < 16; ++jj) {
            float r = fmaxf(h[jj], 0.0f);
            const float* wq = w1 + (jc + jj) * 3;
            o0 = fmaf(r, wq[0], o0);
            o1 = fmaf(r, wq[1], o1);
            o2 = fmaf(r, wq[2], o2);
        }
    }

    long long oo = (long long)myord * 3;
    out[oo + 0] = o0;
    out[oo + 1] = o1;
    out[oo + 2] = o2;
}

// ---------------------------------------------------------------------------
// Fallback (d_ws too small or N not divisible by 64): slow but correct.
// ---------------------------------------------------------------------------
__global__ __launch_bounds__(256) void k_fallback(
    const float4* __restrict__ inp, const float* __restrict__ aabb, PlanePtrs ptrs,
    const float* __restrict__ w0, const float* __restrict__ b0,
    const float* __restrict__ w1, const float* __restrict__ b1,
    float* __restrict__ out, int N, int start)
{
    int pidx = start + blockIdx.x * 256 + threadIdx.x;
    if (pidx >= N) return;
    float4 in = inp[pidx];
    float c[4];
    c[0] = (in.x - aabb[0]) / (aabb[3] - aabb[0]) * 2.0f - 1.0f;
    c[1] = (in.y - aabb[1]) / (aabb[4] - aabb[1]) * 2.0f - 1.0f;
    c[2] = (in.z - aabb[2]) / (aabb[5] - aabb[2]) * 2.0f - 1.0f;
    c[3] = in.w * 2.0f - 1.0f;

    float h[64];
    #pragma unroll
    for (int j = 0; j < 64; ++j) h[j] = b0[j];

    #pragma unroll
    for (int pl = 0; pl < 9; ++pl) {
        const int W = 128, H = g_H[pl];
        float fx = (c[g_A[pl]] + 1.0f) * 0.5f * (float)(W - 1);
        float fy = (c[g_B[pl]] + 1.0f) * 0.5f * (float)(H - 1);
        int x0 = min(max((int)floorf(fx), 0), W - 2);
        int y0 = min(max((int)floorf(fy), 0), H - 2);
        float wx = fx - (float)x0, wy = fy - (float)y0;
        const float* P = ptrs.p[pl];
        int off = y0 * 128 + x0;
        int HW = H * 128;
        int row = (pl < 6) ? 0 : 64;
        for (int f = 0; f < 64; ++f) {
            const float* qp = P + f * HW + off;
            float v = (qp[0] * (1.0f - wx) + qp[1] * wx) * (1.0f - wy)
                    + (qp[128] * (1.0f - wx) + qp[129] * wx) * wy;
            const float* wr = w0 + (row + f) * 64;
            #pragma unroll
            for (int j = 0; j < 64; ++j) h[j] = fmaf(v, wr[j], h[j]);
        }
    }
    float o0 = b1[0], o1 = b1[1], o2 = b1[2];
    #pragma unroll
    for (int j = 0; j < 64; ++j) {
        float r = fmaxf(h[j], 0.0f);
        o0 = fmaf(r, w1[j * 3 + 0], o0);
        o1 = fmaf(r, w1[j * 3 + 1], o1);
        o2 = fmaf(r, w1[j * 3 + 2], o2);
    }
    out[(long long)pidx * 3 + 0] = o0;
    out[(long long)pidx * 3 + 1] = o1;
    out[(long long)pidx * 3 + 2] = o2;
}

// ---------------------------------------------------------------------------
extern "C" void kernel_launch(void* const* d_in, const int* in_sizes, int n_in,
                              void* d_out, int out_size, void* d_ws, size_t ws_size,
                              hipStream_t stream)
{
    const float4* inp  = (const float4*)d_in[0];
    const float*  aabb = (const float*)d_in[1];
    PlanePtrs ptrs;
    for (int i = 0; i < 9; ++i) ptrs.p[i] = (const float*)d_in[2 + i];
    const float* w0 = (const float*)d_in[11];
    const float* b0 = (const float*)d_in[12];
    const float* w1 = (const float*)d_in[13];
    const float* b1 = (const float*)d_in[14];
    float* out = (float*)d_out;
    const int N = in_sizes[0] / 4;

    const size_t off_w0h   = WS_PLANES;
    const size_t ws_base   = WS_PLANES + WS_W0H;
    const size_t off_order = ws_base;
    const size_t off_bh    = off_order + 4ull * (size_t)N;
    const size_t off_bt    = off_bh + (size_t)NHB * NBINS * 4;
    const size_t off_bs    = off_bt + NBINS * 4;
    const size_t need_sort = off_bs + NBINS * 4;

    if (ws_size >= ws_base && (N % 64) == 0) {
        __half* planes = (__half*)d_ws;
        unsigned int* w0h = (unsigned int*)((char*)d_ws + off_w0h);
        k_transpose<<<TOTAL_TEXELS / 256, 256, 0, stream>>>(ptrs, planes);
        k_w0pack<<<16, 256, 0, stream>>>(w0, w0h);

        if (ws_size >= need_sort) {
            int* order    = (int*)((char*)d_ws + off_order);
            int* blkhist  = (int*)((char*)d_ws + off_bh);
            int* bintotal = (int*)((char*)d_ws + off_bt);
            int* binstart = (int*)((char*)d_ws + off_bs);
            int chunk = (((N + NHB - 1) / NHB) + 255) / 256 * 256;

            k_hist2<<<NHB, 256, 0, stream>>>(inp, aabb, N, chunk, blkhist);
            k_scanA<<<NBINS / 256, 256, 0, stream>>>(blkhist, bintotal);
            k_scanB<<<1, 256, 0, stream>>>(bintotal, binstart);
            k_fill2<<<NHB, 256, 0, stream>>>(inp, aabb, N, chunk, blkhist, binstart, order);
            k_main<<<N / 64, 64, 0, stream>>>(inp, aabb, planes, w0h, order, 1,
                                              w0, b0, w1, b1, out);
        } else {
            k_main<<<N / 64, 64, 0, stream>>>(inp, aabb, planes, w0h, (const int*)nullptr, 0,
                                              w0, b0, w1, b1, out);
        }
    } else {
        k_fallback<<<(N + 255) / 256, 256, 0, stream>>>(inp, aabb, ptrs, w0, b0, w1, b1, out, N, 0);
    }
}